// Round 11
// baseline (329.710 us; speedup 1.0000x reference)
//
#include <hip/hip_runtime.h>
#include <hip/hip_bf16.h>

#define D_FEAT 256

typedef __attribute__((ext_vector_type(8))) __bf16 bf16x8;
typedef __attribute__((ext_vector_type(4))) __bf16 bf16x4;
typedef __attribute__((ext_vector_type(4))) float f32x4;

// ---------------------------------------------------------------------------
// Kernel 0: Wt[n][k] = bf16(W[k][n])   (256x256, tiny)
// ---------------------------------------------------------------------------
__global__ __launch_bounds__(256) void cast_wt(
    const float* __restrict__ W, __bf16* __restrict__ Wt) {
  const int n = blockIdx.x;
  const int k = threadIdx.x;
  Wt[n * 256 + k] = (__bf16)W[k * 256 + n];
}

// ---------------------------------------------------------------------------
// Kernel 1: S = bf16( X @ W )  via mfma_f32_16x16x32_bf16   (R8-exact)
// Tile BM=128, BN=128, BK=32; operands SWAPPED (A=Wt rows, B=X rows) so the
// D reg-dim runs along n -> epilogue packs 4 consecutive bf16 per 8B store.
// ---------------------------------------------------------------------------
#define APITCH 40  // bf16 elems per row (pad 32->40; 2-way LDS alias = free)

__global__ __launch_bounds__(256) void gemm_mfma(
    const float* __restrict__ X, const __bf16* __restrict__ Wt,
    __bf16* __restrict__ S, int M) {
  __shared__ __bf16 As[128 * APITCH];  // 10 KiB
  __shared__ __bf16 Bs[128 * APITCH];  // 10 KiB
  const int tid = threadIdx.x;
  const int wave = tid >> 6;
  const int lane = tid & 63;
  const int m0 = blockIdx.y * 128;
  const int n0 = blockIdx.x * 128;

  f32x4 acc[2][8] = {};

  const int l15 = lane & 15;
  const int kh8 = (lane >> 4) * 8;

  const int r = tid >> 1;            // 0..127
  const int kh = (tid & 1) * 16;     // 0 or 16
  const int gr = m0 + r;
  const bool valid = gr < M;
  const float* xsrc = X + (size_t)(valid ? gr : 0) * D_FEAT + kh;

  float4 pre[4];
#pragma unroll
  for (int q = 0; q < 4; ++q)
    pre[q] = valid ? *reinterpret_cast<const float4*>(xsrc + q * 4)
                   : make_float4(0.f, 0.f, 0.f, 0.f);

  const int nr = tid >> 1;           // B staging: 0..127
  const int qb = (tid & 1) * 16;     // 0 or 16

  for (int k0 = 0; k0 < D_FEAT; k0 += 32) {
    const __bf16* wsrc = Wt + (size_t)(n0 + nr) * D_FEAT + k0 + qb;
    bf16x8 wb0 = *reinterpret_cast<const bf16x8*>(wsrc);
    bf16x8 wb1 = *reinterpret_cast<const bf16x8*>(wsrc + 8);

    bf16x8 a0, a1;
    a0[0] = (__bf16)pre[0].x; a0[1] = (__bf16)pre[0].y;
    a0[2] = (__bf16)pre[0].z; a0[3] = (__bf16)pre[0].w;
    a0[4] = (__bf16)pre[1].x; a0[5] = (__bf16)pre[1].y;
    a0[6] = (__bf16)pre[1].z; a0[7] = (__bf16)pre[1].w;
    a1[0] = (__bf16)pre[2].x; a1[1] = (__bf16)pre[2].y;
    a1[2] = (__bf16)pre[2].z; a1[3] = (__bf16)pre[2].w;
    a1[4] = (__bf16)pre[3].x; a1[5] = (__bf16)pre[3].y;
    a1[6] = (__bf16)pre[3].z; a1[7] = (__bf16)pre[3].w;
    *reinterpret_cast<bf16x8*>(&As[r * APITCH + kh]) = a0;
    *reinterpret_cast<bf16x8*>(&As[r * APITCH + kh + 8]) = a1;
    *reinterpret_cast<bf16x8*>(&Bs[nr * APITCH + qb]) = wb0;
    *reinterpret_cast<bf16x8*>(&Bs[nr * APITCH + qb + 8]) = wb1;

    const bool have = (k0 + 32) < D_FEAT;
    float4 nxt[4];
    if (have && valid) {
#pragma unroll
      for (int q = 0; q < 4; ++q)
        nxt[q] = *reinterpret_cast<const float4*>(xsrc + k0 + 32 + q * 4);
    }
    __syncthreads();

    bf16x8 a[2], b[8];
#pragma unroll
    for (int rg = 0; rg < 2; ++rg)
      a[rg] = *reinterpret_cast<const bf16x8*>(
          &As[(wave * 32 + rg * 16 + l15) * APITCH + kh8]);
#pragma unroll
    for (int cg = 0; cg < 8; ++cg)
      b[cg] = *reinterpret_cast<const bf16x8*>(
          &Bs[(cg * 16 + l15) * APITCH + kh8]);
    // Operands swapped: D n = (l>>4)*4 + reg, m = l&15.
#pragma unroll
    for (int rg = 0; rg < 2; ++rg)
#pragma unroll
      for (int cg = 0; cg < 8; ++cg)
        acc[rg][cg] = __builtin_amdgcn_mfma_f32_16x16x32_bf16(
            b[cg], a[rg], acc[rg][cg], 0, 0, 0);
    __syncthreads();

    if (have && valid) {
#pragma unroll
      for (int q = 0; q < 4; ++q) pre[q] = nxt[q];
    }
  }

  // epilogue: lane writes 4 consecutive n as one 8B bf16x4 store
#pragma unroll
  for (int rg = 0; rg < 2; ++rg) {
    const int m = m0 + wave * 32 + rg * 16 + l15;
    if (m < M) {
#pragma unroll
      for (int cg = 0; cg < 8; ++cg) {
        const int nb = n0 + cg * 16 + (lane >> 4) * 4;
        bf16x4 p;
#pragma unroll
        for (int rr = 0; rr < 4; ++rr) p[rr] = (__bf16)acc[rg][cg][rr];
        *reinterpret_cast<bf16x4*>(&S[(size_t)m * D_FEAT + nb]) = p;
      }
    }
  }
}

// ---------------------------------------------------------------------------
// Kernel 3: out[n] = bias + sum val[e]*S[col[e]]   (R8 gather structure)
// Inline rowptr: all lanes binary-search lower_bound(adj_row, n + (lane&1));
// e0/e1 broadcast via shfl. No separate rowptr kernel / buffer.
// ---------------------------------------------------------------------------
__global__ __launch_bounds__(256) void spmm_rows(
    const __bf16* __restrict__ S, const int* __restrict__ rows,
    const int* __restrict__ col, const float* __restrict__ val,
    const float* __restrict__ bias, float* __restrict__ out, int N, int E) {
  const int wave = threadIdx.x >> 6;
  const int lane = threadIdx.x & 63;
  const int n = blockIdx.x * 4 + wave;
  if (n >= N) return;

  // lower_bound(rows, n + (lane&1)): lanes 0/1 give e0/e1 (others redundant)
  {
  }
  const int tgt = n + (lane & 1);
  int lo = 0, hi = E;
  while (lo < hi) {
    const int mid = (lo + hi) >> 1;
    if (rows[mid] < tgt) lo = mid + 1; else hi = mid;
  }
  const int e0 = __shfl(lo, 0, 64);
  const int e1 = __shfl(lo, 1, 64);

  const int hw = lane >> 5;        // 0: even edges, 1: odd edges
  const int f0 = (lane & 31) * 8;  // feature group (8 bf16 = 16B)

  float acc[8] = {};
  const int deg = e1 - e0;
  const int elast = e1 - 1;
  const int nit = (deg + 15) >> 4; // batches of 16 edges (8 per half-wave)

  int e = e0;
  for (int b = 0; b < nit; ++b, e += 16) {
    int cc[8];
    float vv[8];
#pragma unroll
    for (int i = 0; i < 8; ++i) {
      int ee = e + 2 * i + hw;
      const bool ok = ee <= elast;
      ee = ok ? ee : elast;
      cc[i] = col[ee];
      vv[i] = ok ? val[ee] : 0.f;
    }
#pragma unroll
    for (int i = 0; i < 8; ++i) {
      bf16x8 s = *reinterpret_cast<const bf16x8*>(S + (size_t)cc[i] * D_FEAT + f0);
#pragma unroll
      for (int j = 0; j < 8; ++j) acc[j] += vv[i] * (float)s[j];
    }
  }

  // combine half-waves: partner lane is lane ^ 32
#pragma unroll
  for (int j = 0; j < 8; ++j) acc[j] += __shfl(acc[j], lane ^ 32, 64);

  // lane (hw, l5) writes float4 at feature f0 + hw*4 (static acc indexing)
  const int fw = f0 + hw * 4;
  const float4 b = *reinterpret_cast<const float4*>(bias + fw);
  const float r0 = hw ? acc[4] : acc[0];
  const float r1 = hw ? acc[5] : acc[1];
  const float r2 = hw ? acc[6] : acc[2];
  const float r3 = hw ? acc[7] : acc[3];
  f32x4 o;
  o[0] = r0 + b.x; o[1] = r1 + b.y; o[2] = r2 + b.z; o[3] = r3 + b.w;
  __builtin_nontemporal_store(
      o, reinterpret_cast<f32x4*>(out + (size_t)n * D_FEAT + fw));
}

// ---------------------------------------------------------------------------
extern "C" void kernel_launch(void* const* d_in, const int* in_sizes, int n_in,
                              void* d_out, int out_size, void* d_ws, size_t ws_size,
                              hipStream_t stream) {
  const float* x       = (const float*)d_in[0];
  const int*   adj_row = (const int*)d_in[1];
  const int*   adj_col = (const int*)d_in[2];
  const float* adj_val = (const float*)d_in[3];
  const float* weight  = (const float*)d_in[4];
  const float* bias    = (const float*)d_in[5];
  float*       out     = (float*)d_out;

  const int N = in_sizes[0] / D_FEAT;   // 100000
  const int E = in_sizes[1];            // 3200000

  // ws layout: Wt bf16 [256*256] | support bf16 [N*256]
  __bf16* Wt      = (__bf16*)d_ws;
  __bf16* support = Wt + 256 * 256;

  cast_wt<<<256, 256, 0, stream>>>(weight, Wt);

  {
    dim3 grid(D_FEAT / 128, (N + 127) / 128);
    gemm_mfma<<<grid, 256, 0, stream>>>(x, Wt, support, N);
  }
  {
    const int blocks = (N + 3) / 4;
    spmm_rows<<<blocks, 256, 0, stream>>>(support, adj_row, adj_col, adj_val,
                                          bias, out, N, E);
  }
}

// Round 12
// 277.964 us; speedup vs baseline: 1.1862x; 1.1862x over previous
//
#include <hip/hip_runtime.h>
#include <hip/hip_bf16.h>

#define D_FEAT 256

typedef __attribute__((ext_vector_type(8))) __bf16 bf16x8;
typedef __attribute__((ext_vector_type(4))) __bf16 bf16x4;
typedef __attribute__((ext_vector_type(4))) float f32x4;

// ---------------------------------------------------------------------------
// Kernel A (fused prep): blocks [0,RB) build rowptr via binary search on the
// sorted adj_row; blocks [RB, RB+256) transpose-cast W -> Wt bf16.
// ---------------------------------------------------------------------------
__global__ __launch_bounds__(256) void prep(
    const int* __restrict__ rows, int E, int* __restrict__ ptr, int N,
    const float* __restrict__ W, __bf16* __restrict__ Wt, int RB) {
  const int b = blockIdx.x;
  if (b < RB) {
    const int n = b * 256 + threadIdx.x;
    if (n > N) return;
    int lo = 0, hi = E;
    while (lo < hi) {
      const int mid = (lo + hi) >> 1;
      if (rows[mid] < n) lo = mid + 1; else hi = mid;
    }
    ptr[n] = lo;
  } else {
    const int n = b - RB;          // 0..255
    const int k = threadIdx.x;     // 0..255
    Wt[n * 256 + k] = (__bf16)W[k * 256 + n];
  }
}

// ---------------------------------------------------------------------------
// Kernel 1: S = bf16( X @ W )  via mfma_f32_16x16x32_bf16
// Tile BM=128, BN=128, BK=32; operands SWAPPED (A=Wt rows, B=X rows) so the
// D reg-dim runs along n -> epilogue packs 4 consecutive bf16 per 8B store.
// ---------------------------------------------------------------------------
#define APITCH 40  // bf16 elems per row (pad 32->40; 2-way LDS alias = free)

__global__ __launch_bounds__(256) void gemm_mfma(
    const float* __restrict__ X, const __bf16* __restrict__ Wt,
    __bf16* __restrict__ S, int M) {
  __shared__ __bf16 As[128 * APITCH];  // 10 KiB
  __shared__ __bf16 Bs[128 * APITCH];  // 10 KiB
  const int tid = threadIdx.x;
  const int wave = tid >> 6;
  const int lane = tid & 63;
  const int m0 = blockIdx.y * 128;
  const int n0 = blockIdx.x * 128;

  f32x4 acc[2][8] = {};

  const int l15 = lane & 15;
  const int kh8 = (lane >> 4) * 8;

  const int r = tid >> 1;            // 0..127
  const int kh = (tid & 1) * 16;     // 0 or 16
  const int gr = m0 + r;
  const bool valid = gr < M;
  const float* xsrc = X + (size_t)(valid ? gr : 0) * D_FEAT + kh;

  float4 pre[4];
#pragma unroll
  for (int q = 0; q < 4; ++q)
    pre[q] = valid ? *reinterpret_cast<const float4*>(xsrc + q * 4)
                   : make_float4(0.f, 0.f, 0.f, 0.f);

  const int nr = tid >> 1;           // B staging: 0..127
  const int qb = (tid & 1) * 16;     // 0 or 16

  for (int k0 = 0; k0 < D_FEAT; k0 += 32) {
    const __bf16* wsrc = Wt + (size_t)(n0 + nr) * D_FEAT + k0 + qb;
    bf16x8 wb0 = *reinterpret_cast<const bf16x8*>(wsrc);
    bf16x8 wb1 = *reinterpret_cast<const bf16x8*>(wsrc + 8);

    bf16x8 a0, a1;
    a0[0] = (__bf16)pre[0].x; a0[1] = (__bf16)pre[0].y;
    a0[2] = (__bf16)pre[0].z; a0[3] = (__bf16)pre[0].w;
    a0[4] = (__bf16)pre[1].x; a0[5] = (__bf16)pre[1].y;
    a0[6] = (__bf16)pre[1].z; a0[7] = (__bf16)pre[1].w;
    a1[0] = (__bf16)pre[2].x; a1[1] = (__bf16)pre[2].y;
    a1[2] = (__bf16)pre[2].z; a1[3] = (__bf16)pre[2].w;
    a1[4] = (__bf16)pre[3].x; a1[5] = (__bf16)pre[3].y;
    a1[6] = (__bf16)pre[3].z; a1[7] = (__bf16)pre[3].w;
    *reinterpret_cast<bf16x8*>(&As[r * APITCH + kh]) = a0;
    *reinterpret_cast<bf16x8*>(&As[r * APITCH + kh + 8]) = a1;
    *reinterpret_cast<bf16x8*>(&Bs[nr * APITCH + qb]) = wb0;
    *reinterpret_cast<bf16x8*>(&Bs[nr * APITCH + qb + 8]) = wb1;

    const bool have = (k0 + 32) < D_FEAT;
    float4 nxt[4];
    if (have && valid) {
#pragma unroll
      for (int q = 0; q < 4; ++q)
        nxt[q] = *reinterpret_cast<const float4*>(xsrc + k0 + 32 + q * 4);
    }
    __syncthreads();

    bf16x8 a[2], b[8];
#pragma unroll
    for (int rg = 0; rg < 2; ++rg)
      a[rg] = *reinterpret_cast<const bf16x8*>(
          &As[(wave * 32 + rg * 16 + l15) * APITCH + kh8]);
#pragma unroll
    for (int cg = 0; cg < 8; ++cg)
      b[cg] = *reinterpret_cast<const bf16x8*>(
          &Bs[(cg * 16 + l15) * APITCH + kh8]);
    // Operands swapped: D n = (l>>4)*4 + reg, m = l&15.
#pragma unroll
    for (int rg = 0; rg < 2; ++rg)
#pragma unroll
      for (int cg = 0; cg < 8; ++cg)
        acc[rg][cg] = __builtin_amdgcn_mfma_f32_16x16x32_bf16(
            b[cg], a[rg], acc[rg][cg], 0, 0, 0);
    __syncthreads();

    if (have && valid) {
#pragma unroll
      for (int q = 0; q < 4; ++q) pre[q] = nxt[q];
    }
  }

  // epilogue: lane writes 4 consecutive n as one 8B bf16x4 store
#pragma unroll
  for (int rg = 0; rg < 2; ++rg) {
    const int m = m0 + wave * 32 + rg * 16 + l15;
    if (m < M) {
#pragma unroll
      for (int cg = 0; cg < 8; ++cg) {
        const int nb = n0 + cg * 16 + (lane >> 4) * 4;
        bf16x4 p;
#pragma unroll
        for (int rr = 0; rr < 4; ++rr) p[rr] = (__bf16)acc[rg][cg][rr];
        *reinterpret_cast<bf16x4*>(&S[(size_t)m * D_FEAT + nb]) = p;
      }
    }
  }
}

// ---------------------------------------------------------------------------
// Kernel 3: out[n] = bias + sum val[e]*S[col[e]]   (R5/R8 structure, verbatim)
// Wave per node; half-wave h = edges of parity h; lane = 8 feats (16B).
// ALL batches are full 8-gather batches: index-clamped loads, masked val.
// ---------------------------------------------------------------------------
__global__ __launch_bounds__(256) void spmm_rows(
    const __bf16* __restrict__ S, const int* __restrict__ ptr,
    const int* __restrict__ col, const float* __restrict__ val,
    const float* __restrict__ bias, float* __restrict__ out, int N) {
  const int wave = threadIdx.x >> 6;
  const int lane = threadIdx.x & 63;
  const int n = blockIdx.x * 4 + wave;
  if (n >= N) return;

  const int e0 = ptr[n];
  const int e1 = ptr[n + 1];
  const int hw = lane >> 5;        // 0: even edges, 1: odd edges
  const int f0 = (lane & 31) * 8;  // feature group (8 bf16 = 16B)

  float acc[8] = {};
  const int deg = e1 - e0;
  const int elast = e1 - 1;
  const int nit = (deg + 15) >> 4; // batches of 16 edges (8 per half-wave)

  int e = e0;
  for (int b = 0; b < nit; ++b, e += 16) {
    int cc[8];
    float vv[8];
#pragma unroll
    for (int i = 0; i < 8; ++i) {
      int ee = e + 2 * i + hw;
      const bool ok = ee <= elast;
      ee = ok ? ee : elast;
      cc[i] = col[ee];
      vv[i] = ok ? val[ee] : 0.f;
    }
#pragma unroll
    for (int i = 0; i < 8; ++i) {
      bf16x8 s = *reinterpret_cast<const bf16x8*>(S + (size_t)cc[i] * D_FEAT + f0);
#pragma unroll
      for (int j = 0; j < 8; ++j) acc[j] += vv[i] * (float)s[j];
    }
  }

  // combine half-waves: partner lane is lane ^ 32
#pragma unroll
  for (int j = 0; j < 8; ++j) acc[j] += __shfl(acc[j], lane ^ 32, 64);

  // lane (hw, l5) writes float4 at feature f0 + hw*4 (static acc indexing)
  const int fw = f0 + hw * 4;
  const float4 b = *reinterpret_cast<const float4*>(bias + fw);
  const float r0 = hw ? acc[4] : acc[0];
  const float r1 = hw ? acc[5] : acc[1];
  const float r2 = hw ? acc[6] : acc[2];
  const float r3 = hw ? acc[7] : acc[3];
  f32x4 o;
  o[0] = r0 + b.x; o[1] = r1 + b.y; o[2] = r2 + b.z; o[3] = r3 + b.w;
  __builtin_nontemporal_store(
      o, reinterpret_cast<f32x4*>(out + (size_t)n * D_FEAT + fw));
}

// ---------------------------------------------------------------------------
extern "C" void kernel_launch(void* const* d_in, const int* in_sizes, int n_in,
                              void* d_out, int out_size, void* d_ws, size_t ws_size,
                              hipStream_t stream) {
  const float* x       = (const float*)d_in[0];
  const int*   adj_row = (const int*)d_in[1];
  const int*   adj_col = (const int*)d_in[2];
  const float* adj_val = (const float*)d_in[3];
  const float* weight  = (const float*)d_in[4];
  const float* bias    = (const float*)d_in[5];
  float*       out     = (float*)d_out;

  const int N = in_sizes[0] / D_FEAT;   // 100000
  const int E = in_sizes[1];            // 3200000

  // ws layout: Wt bf16 [256*256] | support bf16 [N*256] | rowptr int [N+1]
  __bf16* Wt      = (__bf16*)d_ws;
  __bf16* support = Wt + 256 * 256;
  int*    rowptr  = (int*)(support + (size_t)N * D_FEAT);

  const int RB = (N + 1 + 255) / 256;   // rowptr blocks
  prep<<<RB + 256, 256, 0, stream>>>(adj_row, E, rowptr, N, weight, Wt, RB);

  {
    dim3 grid(D_FEAT / 128, (N + 127) / 128);
    gemm_mfma<<<grid, 256, 0, stream>>>(x, Wt, support, N);
  }
  {
    const int blocks = (N + 3) / 4;
    spmm_rows<<<blocks, 256, 0, stream>>>(support, rowptr, adj_col, adj_val,
                                          bias, out, N);
  }
}